// Round 7
// baseline (145.329 us; speedup 1.0000x reference)
//
#include <hip/hip_runtime.h>

// B=4, C=128, H=4, D=32, N=2048.  All-fp16 MFMA pipeline, canonical packed
// fragment format: value block (16ch tile ct, col n, quad q) lives at
// pk[(ct*2048+n)*16 + q*4 + j].
// R9: attn 4-way split + LDS mask bias (161.2).
// R10: 32-col blocks in qkv/post, weight reuse for 2 col groups (143.1).
// R11: prep kernel pre-converts weights to fp16 once (142.5).
// R12: attn denominator on VALU; post kt-paired b128 weight loads (139.5).
// R13: K=32 MFMA everywhere.  post: kt-paired half8 weight IS the K=32
// A-frag; B-frag = concat of the two existing half4 LDS reads -> 112->56
// MFMA/wave, zero new LDS ops.  attn PV: K-staging rows permuted
// (kk -> tile[(kk>>2)&1], row 4*((kk>>3)&3)+(kk&3)) so QK C-rows carry keys
// {32mt2+8q+4par+j}; concat(pB[2mt2],pB[2mt2+1]) is then the natural-order
// K=32 B-frag and V reads become 4 half8 -> PV 16->8 MFMA/chunk/wave.
// Bias C-init re-indexed to the same permutation; lsum/O invariant.
typedef __attribute__((ext_vector_type(4))) float v4f;
typedef __attribute__((ext_vector_type(8))) _Float16 half8;
typedef __attribute__((ext_vector_type(4))) _Float16 half4;
typedef __attribute__((ext_vector_type(2))) _Float16 half2t;

constexpr float C2 = 0.17677669529663687f * 1.44269504088896341f;  // rsqrt(32)*log2e

__device__ __forceinline__ half4 pk4(float a, float b, float c, float d) {
  half2t lo = __builtin_bit_cast(half2t, __builtin_amdgcn_cvt_pkrtz(a, b));
  half2t hi = __builtin_bit_cast(half2t, __builtin_amdgcn_cvt_pkrtz(c, d));
  return __builtin_shufflevector(lo, hi, 0, 1, 2, 3);
}
__device__ __forceinline__ half8 cat8(const half4 a, const half4 b) {
  return __builtin_shufflevector(a, b, 0, 1, 2, 3, 4, 5, 6, 7);
}

// ---------------------------------------------------------------------------
// prep: one-shot weight/mask conversion.  wq|wk|wv -> wqkvh (49152 floats,
// linear).  wm|wc1|wc2 -> wts (147456) with KT-PAIRED layout: within each
// row, dst = (kt>>1)*32 + q4*8 + (kt&1)*4 + j.  mask -> maskf (8192).
// grid 100 x 512.  [unchanged from R12]
// ---------------------------------------------------------------------------
__global__ __launch_bounds__(512) void prep(
    const float* __restrict__ wq, const float* __restrict__ wk,
    const float* __restrict__ wv, const float* __restrict__ wm,
    const float* __restrict__ wc1, const float* __restrict__ wc2,
    const unsigned char* __restrict__ mask, _Float16* __restrict__ wqkvh,
    _Float16* __restrict__ wts, float* __restrict__ maskf) {
  const int e = (blockIdx.x * 512 + threadIdx.x) * 4;
  if (e < 49152) {
    const float* src;
    int base;
    if (e < 16384) { src = wq; base = 0; }
    else if (e < 32768) { src = wk; base = 16384; }
    else { src = wv; base = 32768; }
    const float4 t = *(const float4*)(src + (e - base));
    *(half4*)(wqkvh + e) = pk4(t.x, t.y, t.z, t.w);
  } else if (e < 196608) {
    const int e2 = e - 49152;
    const float* src;
    int base, cols;
    if (e2 < 16384) { src = wm; base = 0; cols = 128; }
    else if (e2 < 81920) { src = wc1; base = 16384; cols = 256; }
    else { src = wc2; base = 81920; cols = 256; }
    const int le = e2 - base;
    const int r = le / cols, c = le % cols;
    const int kt = c >> 4, q4 = (c >> 2) & 3;
    const int dst = r * cols + ((kt >> 1) << 5) + (q4 << 3) + ((kt & 1) << 2);
    const float4 t = *(const float4*)(src + le);
    *(half4*)(wts + base + dst) = pk4(t.x, t.y, t.z, t.w);
  } else {
    const int e2 = e - 196608;  // < 8192
    const unsigned mv = *(const unsigned*)(mask + e2);
    float4 o;
    o.x = (mv & 0x000000ffu) ? 0.f : -1.0e6f * C2;
    o.y = (mv & 0x0000ff00u) ? 0.f : -1.0e6f * C2;
    o.z = (mv & 0x00ff0000u) ? 0.f : -1.0e6f * C2;
    o.w = (mv & 0xff000000u) ? 0.f : -1.0e6f * C2;
    *(float4*)(maskf + e2) = o;
  }
}

// ---------------------------------------------------------------------------
// qkv: 32-col blocks, 8 waves; wave w owns 3 of 24 output tiles
// (Q0..7,K8..15,V16..23), each applied to both 16-col groups g=0,1 with ONE
// weight load (fp16, pre-converted).  x1/x2 tiles staged through LDS as fp16
// [g][n][ch] (stride 136).  grid (64,4) x 512.  [unchanged from R12]
// ---------------------------------------------------------------------------
__global__ __launch_bounds__(512, 4) void qkv(
    const float* __restrict__ x1, const float* __restrict__ x2,
    const _Float16* __restrict__ wqkvh, const float* __restrict__ bq,
    const float* __restrict__ bk, const float* __restrict__ bv,
    _Float16* __restrict__ Qpk, _Float16* __restrict__ Kpk,
    _Float16* __restrict__ Vpk) {
  const int b = blockIdx.y;
  const int bx = blockIdx.x;  // 32-col group
  const int tid = threadIdx.x, w = tid >> 6, lane = tid & 63;
  const int l = lane & 15, q = lane >> 4;
  const int n0 = bx * 32;
  const _Float16* wqh = wqkvh;
  const _Float16* wkh = wqkvh + 16384;
  const _Float16* wvh = wqkvh + 32768;

  __shared__ _Float16 x1s[2][16 * 136];
  __shared__ _Float16 x2s[2][16 * 136];

  {  // stage x tiles: thread -> (ch, 4 cols) per group, fp32->fp16
    const int ch = tid >> 2, seg = tid & 3;
#pragma unroll
    for (int g = 0; g < 2; ++g) {
      const float4 a =
          *(const float4*)(x1 + (size_t)(b * 128 + ch) * 2048 + n0 + g * 16 + seg * 4);
      const float4 c =
          *(const float4*)(x2 + (size_t)(b * 128 + ch) * 2048 + n0 + g * 16 + seg * 4);
      x1s[g][(seg * 4 + 0) * 136 + ch] = (_Float16)a.x;
      x1s[g][(seg * 4 + 1) * 136 + ch] = (_Float16)a.y;
      x1s[g][(seg * 4 + 2) * 136 + ch] = (_Float16)a.z;
      x1s[g][(seg * 4 + 3) * 136 + ch] = (_Float16)a.w;
      x2s[g][(seg * 4 + 0) * 136 + ch] = (_Float16)c.x;
      x2s[g][(seg * 4 + 1) * 136 + ch] = (_Float16)c.y;
      x2s[g][(seg * 4 + 2) * 136 + ch] = (_Float16)c.z;
      x2s[g][(seg * 4 + 3) * 136 + ch] = (_Float16)c.w;
    }
  }
  __syncthreads();

#pragma unroll
  for (int i = 0; i < 3; ++i) {
    const int t = w * 3 + i;  // wave-uniform
    if (t < 8) {              // Q tile mt=t : out = C2*(wq@x1 + bq)
      const int mt = t;
      half8 wf[4];
#pragma unroll
      for (int kt = 0; kt < 4; ++kt)
        wf[kt] = *(const half8*)(wqh + (mt * 16 + l) * 128 + kt * 32 + q * 8);
      const v4f bias = *(const v4f*)(bq + mt * 16 + q * 4);
#pragma unroll
      for (int g = 0; g < 2; ++g) {
        v4f acc = bias;
#pragma unroll
        for (int kt = 0; kt < 4; ++kt) {
          const half8 xf = *(const half8*)&x1s[g][l * 136 + kt * 32 + q * 8];
          acc = __builtin_amdgcn_mfma_f32_16x16x32_f16(wf[kt], xf, acc, 0, 0, 0);
        }
        *(half4*)(Qpk + ((size_t)(b * 8 + mt) * 2048 + n0 + g * 16 + l) * 16 + q * 4) =
            pk4(acc[0] * C2, acc[1] * C2, acc[2] * C2, acc[3] * C2);
      }
    } else if (t < 16) {  // K tile
      const int mt = t - 8;
      half8 wf[4];
#pragma unroll
      for (int kt = 0; kt < 4; ++kt)
        wf[kt] = *(const half8*)(wkh + (mt * 16 + l) * 128 + kt * 32 + q * 8);
      const v4f bias = *(const v4f*)(bk + mt * 16 + q * 4);
#pragma unroll
      for (int g = 0; g < 2; ++g) {
        v4f acc = bias;
#pragma unroll
        for (int kt = 0; kt < 4; ++kt) {
          const half8 xf = *(const half8*)&x2s[g][l * 136 + kt * 32 + q * 8];
          acc = __builtin_amdgcn_mfma_f32_16x16x32_f16(wf[kt], xf, acc, 0, 0, 0);
        }
        *(half4*)(Kpk + ((size_t)(b * 8 + mt) * 2048 + n0 + g * 16 + l) * 16 + q * 4) =
            pk4(acc[0], acc[1], acc[2], acc[3]);
      }
    } else {  // V^T tile ot (rows = keys of this col-group)
      const int ot = t - 16;
      half8 wf[4];
#pragma unroll
      for (int kt = 0; kt < 4; ++kt)
        wf[kt] = *(const half8*)(wvh + (ot * 16 + l) * 128 + kt * 32 + q * 8);
      const float bvv = bv[ot * 16 + l];
#pragma unroll
      for (int g = 0; g < 2; ++g) {
        v4f acc = {bvv, bvv, bvv, bvv};
#pragma unroll
        for (int kt = 0; kt < 4; ++kt) {
          const half8 xf = *(const half8*)&x2s[g][l * 136 + kt * 32 + q * 8];
          acc = __builtin_amdgcn_mfma_f32_16x16x32_f16(xf, wf[kt], acc, 0, 0, 0);
        }
        const int kx = bx * 2 + g;  // 16-col keytile index
        *(half4*)(Vpk + (((size_t)(b * 4 + (ot >> 1)) * 128 + kx) * 32 +
                         (ot & 1) * 16 + l) * 16 + q * 4) =
            pk4(acc[0], acc[1], acc[2], acc[3]);
      }
    }
  }
}

// ---------------------------------------------------------------------------
// attn: 2 Q-tiles per wave, 4-way key split (512 keys/part, 8 chunks).
// K/V chunks (64 keys) staged in LDS, double-buffered, ONE barrier per chunk.
// R13: K rows stored PERMUTED (key kk -> tile 2*(kk>>5)+((kk>>2)&1), row
// 4*((kk>>3)&3)+(kk&3)); QK C-rows then carry keys 32mt2+8q+4par+j, so
// concat(pB[2mt2],pB[2mt2+1]) is the natural-order K=32 PV B-frag: PV = 8
// mfma_16x16x32 + 4 half8 V reads per chunk (was 16 K=16 + 8 half4).
// Bias C-init re-indexed to match.  Denominator on VALU.  s_setprio around
// MFMA clusters.  grid (16,16,4) x 256.
// ---------------------------------------------------------------------------
__global__ __launch_bounds__(256) void attn(
    const _Float16* __restrict__ Qpk, const _Float16* __restrict__ Kpk,
    const _Float16* __restrict__ Vpk, const float* __restrict__ maskf,
    _Float16* __restrict__ Opk, float* __restrict__ lsump) {
  const int bh = blockIdx.y, b = bh >> 2, h = bh & 3;
  const int part = blockIdx.z;
  const int tid = threadIdx.x, w = tid >> 6, lane = tid & 63;
  const int l = lane & 15, q = lane >> 4;
  const int nb = blockIdx.x * 128 + w * 32;  // wave's 32 queries

  // K: [ct][row][16] rows padded to 24 halfs, ct stride 1544 (bank-skewed).
  // V: [tile][d][16] rows padded to 24 halfs, tile stride 768.
  __shared__ _Float16 ldsK[2][3088];
  __shared__ _Float16 ldsV[2][3072];
  __shared__ __align__(16) float biass[512];  // part's mask bias (2 KB)

  const size_t qrow = (size_t)(b * 8 + h * 2 + (q >> 1)) * 2048;
  const half8 qf0 = *(const half8*)(Qpk + (qrow + nb + l) * 16 + (q & 1) * 8);
  const half8 qf1 = *(const half8*)(Qpk + (qrow + nb + 16 + l) * 16 + (q & 1) * 8);
  const _Float16* __restrict__ Kg = Kpk + (size_t)(b * 8 + h * 2) * 2048 * 16;
  const _Float16* __restrict__ Vg = Vpk + (size_t)((b * 4 + h) * 128) * 512;

  // staging indices (thread-static); K row permutation for K=32 PV frags
  const int kct = tid >> 7, kk = (tid >> 1) & 63, khf = tid & 1;
  const int krow = ((kk >> 5) * 2 + ((kk >> 2) & 1)) * 16 +
                   ((kk >> 3) & 3) * 4 + (kk & 3);
  const int vt = tid >> 6, vd = (tid >> 1) & 31;

  v4f oacc[2][2] = {{{0.f, 0.f, 0.f, 0.f}, {0.f, 0.f, 0.f, 0.f}},
                    {{0.f, 0.f, 0.f, 0.f}, {0.f, 0.f, 0.f, 0.f}}};
  float ls0 = 0.f, ls1 = 0.f;
  const int mbeg = part * 512;

  // stage bias (2 KB) + first K/V chunk
  if (tid < 128)
    *(float4*)&biass[tid * 4] = *(const float4*)(maskf + b * 2048 + mbeg + tid * 4);
  half8 kr = *(const half8*)(Kg + ((size_t)kct * 2048 + mbeg + kk) * 16 + khf * 8);
  half8 vr = *(const half8*)(Vg + (size_t)((mbeg >> 4) + vt) * 512 + vd * 16 + khf * 8);
  *(half8*)&ldsK[0][kct * 1544 + krow * 24 + khf * 8] = kr;
  *(half8*)&ldsV[0][vt * 768 + vd * 24 + khf * 8] = vr;
  __syncthreads();

  for (int i = 0; i < 8; ++i) {
    const int m0 = mbeg + i * 64;
    const int cur = i & 1;
    if (i < 7) {  // prefetch next chunk to regs
      kr = *(const half8*)(Kg + ((size_t)kct * 2048 + m0 + 64 + kk) * 16 + khf * 8);
      vr = *(const half8*)(Vg + (size_t)(((m0 + 64) >> 4) + vt) * 512 + vd * 16 + khf * 8);
    }
    half4 pB[2][4];
#pragma unroll
    for (int mt = 0; mt < 4; ++mt) {
      const half8 kf =
          *(const half8*)&ldsK[cur][(q >> 1) * 1544 + (mt * 16 + l) * 24 + (q & 1) * 8];
      // C-row q*4+j of permuted tile mt = key 32*(mt>>1) + 8q + 4*(mt&1) + j
      const v4f biasv =
          *(const v4f*)&biass[i * 64 + (mt >> 1) * 32 + q * 8 + (mt & 1) * 4];
      __builtin_amdgcn_s_setprio(1);
      const v4f s0 = __builtin_amdgcn_mfma_f32_16x16x32_f16(kf, qf0, biasv, 0, 0, 0);
      const v4f s1 = __builtin_amdgcn_mfma_f32_16x16x32_f16(kf, qf1, biasv, 0, 0, 0);
      __builtin_amdgcn_s_setprio(0);
      const float a0 = exp2f(s0[0]), a1 = exp2f(s0[1]), a2 = exp2f(s0[2]),
                  a3 = exp2f(s0[3]);
      const float c0 = exp2f(s1[0]), c1 = exp2f(s1[1]), c2 = exp2f(s1[2]),
                  c3 = exp2f(s1[3]);
      ls0 += (a0 + a1) + (a2 + a3);
      ls1 += (c0 + c1) + (c2 + c3);
      pB[0][mt] = pk4(a0, a1, a2, a3);
      pB[1][mt] = pk4(c0, c1, c2, c3);
    }
    __builtin_amdgcn_s_setprio(1);
#pragma unroll
    for (int mt2 = 0; mt2 < 2; ++mt2) {
      const int vtile = mt2 * 2 + (q >> 1);
      const half8 vf0 =
          *(const half8*)&ldsV[cur][vtile * 768 + l * 24 + (q & 1) * 8];
      const half8 vf1 =
          *(const half8*)&ldsV[cur][vtile * 768 + (16 + l) * 24 + (q & 1) * 8];
      const half8 p0 = cat8(pB[0][mt2 * 2], pB[0][mt2 * 2 + 1]);
      const half8 p1 = cat8(pB[1][mt2 * 2], pB[1][mt2 * 2 + 1]);
      oacc[0][0] = __builtin_amdgcn_mfma_f32_16x16x32_f16(vf0, p0, oacc[0][0], 0, 0, 0);
      oacc[0][1] = __builtin_amdgcn_mfma_f32_16x16x32_f16(vf1, p0, oacc[0][1], 0, 0, 0);
      oacc[1][0] = __builtin_amdgcn_mfma_f32_16x16x32_f16(vf0, p1, oacc[1][0], 0, 0, 0);
      oacc[1][1] = __builtin_amdgcn_mfma_f32_16x16x32_f16(vf1, p1, oacc[1][1], 0, 0, 0);
    }
    __builtin_amdgcn_s_setprio(0);
    if (i < 7) {
      *(half8*)&ldsK[cur ^ 1][kct * 1544 + krow * 24 + khf * 8] = kr;
      *(half8*)&ldsV[cur ^ 1][vt * 768 + vd * 24 + khf * 8] = vr;
      __syncthreads();
    }
  }
  ls0 += __shfl_xor(ls0, 16);
  ls0 += __shfl_xor(ls0, 32);
  ls1 += __shfl_xor(ls1, 16);
  ls1 += __shfl_xor(ls1, 32);
  if (q == 0) {
    lsump[part * 32768 + bh * 2048 + nb + l] = ls0;
    lsump[part * 32768 + bh * 2048 + nb + 16 + l] = ls1;
  }
#pragma unroll
  for (int qt = 0; qt < 2; ++qt)
#pragma unroll
    for (int df = 0; df < 2; ++df)
      *(half4*)(Opk + (size_t)part * 1048576 +
                ((size_t)(b * 8 + h * 2 + df) * 2048 + nb + qt * 16 + l) * 16 +
                q * 4) = pk4(oacc[qt][df][0], oacc[qt][df][1], oacc[qt][df][2],
                             oacc[qt][df][3]);
}

// ---------------------------------------------------------------------------
// post: 32-col blocks, 8 waves; kt-paired half8 weight IS the K=32 A-frag;
// B-frag = concat of the two half4 LDS frag reads -> one mfma_16x16x32 per
// kt-pair per group (56 MFMA/wave, was 112).  O-merge, x1 staged once per
// block; cat frags unified in catl.  A: wave w -> cat tile 8+w.  B: wave w
// -> h1 tiles 2w,2w+1 (BN inline).  C: wave w -> out tile w.
// grid (64,4) x 512.
// ---------------------------------------------------------------------------
__global__ __launch_bounds__(512, 4) void post(
    const float* __restrict__ x1, const _Float16* __restrict__ Opk,
    const float* __restrict__ lsump, const _Float16* __restrict__ wts,
    const float* __restrict__ bm, const float* __restrict__ bc1,
    const float* __restrict__ gamma, const float* __restrict__ beta,
    const float* __restrict__ mean, const float* __restrict__ var,
    const float* __restrict__ bc2, float* __restrict__ out) {
  const int b = blockIdx.y;
  const int n0 = blockIdx.x * 32;
  const int tid = threadIdx.x, w = tid >> 6, lane = tid & 63;
  const int l = lane & 15, q = lane >> 4;
  const _Float16* wm_h = wts;
  const _Float16* wc1_h = wts + 16384;
  const _Float16* wc2_h = wts + 81920;

  __shared__ __align__(16) float x1s[2][16 * 132];     // [g][n][ch] fp32
  __shared__ __align__(16) _Float16 ofs[2][8 * 256];   // merged O
  __shared__ __align__(16) _Float16 catl[2][16 * 256]; // cat frags: x1 | A-out
  __shared__ __align__(16) _Float16 exB[2][16 * 256];  // phase-B outputs

  {  // stage x1 tiles: one float4/thread per group
    const int ch = tid >> 2, seg = tid & 3;
#pragma unroll
    for (int g = 0; g < 2; ++g) {
      const float4 a =
          *(const float4*)(x1 + (size_t)(b * 128 + ch) * 2048 + n0 + g * 16 + seg * 4);
      x1s[g][(seg * 4 + 0) * 132 + ch] = a.x;
      x1s[g][(seg * 4 + 1) * 132 + ch] = a.y;
      x1s[g][(seg * 4 + 2) * 132 + ch] = a.z;
      x1s[g][(seg * 4 + 3) * 132 + ch] = a.w;
    }
  }
  {  // merge O parts once: wave w handles ch-tile kt=w
#pragma unroll
    for (int g = 0; g < 2; ++g) {
      const int n = n0 + g * 16 + l;
      const size_t idx = (size_t)(b * 4 + (w >> 1)) * 2048 + n;
      const float rl = 1.0f / (lsump[idx] + lsump[32768 + idx] +
                               lsump[65536 + idx] + lsump[98304 + idx]);
      const size_t oa = ((size_t)(b * 8 + w) * 2048 + n) * 16 + q * 4;
      const half4 a = *(const half4*)(Opk + oa);
      const half4 c = *(const half4*)(Opk + 1048576 + oa);
      const half4 d = *(const half4*)(Opk + 2097152 + oa);
      const half4 e = *(const half4*)(Opk + 3145728 + oa);
      const _Float16 rh = (_Float16)rl;
      const half4 rl4 = {rh, rh, rh, rh};
      *(half4*)&ofs[g][w * 256 + l * 16 + q * 4] = ((a + c) + (d + e)) * rl4;
    }
  }
  __syncthreads();
  {  // x1 fp16 frags into catl tiles 0..7 (x1s complete after sync)
#pragma unroll
    for (int g = 0; g < 2; ++g) {
      const float4 xv = *(const float4*)&x1s[g][l * 132 + w * 16 + q * 4];
      *(half4*)&catl[g][w * 256 + l * 16 + q * 4] = pk4(xv.x, xv.y, xv.z, xv.w);
    }
  }
  {  // phase A: cat tile 8+w = wm @ O  (K=32: wp = A-frag, concat B)
    const v4f bias = *(const v4f*)(bm + w * 16 + q * 4);
    v4f acc[2] = {bias, bias};
#pragma unroll
    for (int kt2 = 0; kt2 < 4; ++kt2) {
      const half8 wp = *(const half8*)(wm_h + (w * 16 + l) * 128 + kt2 * 32 + q * 8);
#pragma unroll
      for (int g = 0; g < 2; ++g) {
        const half4 of0 = *(const half4*)&ofs[g][(kt2 * 2) * 256 + l * 16 + q * 4];
        const half4 of1 = *(const half4*)&ofs[g][(kt2 * 2 + 1) * 256 + l * 16 + q * 4];
        acc[g] = __builtin_amdgcn_mfma_f32_16x16x32_f16(wp, cat8(of0, of1), acc[g], 0, 0, 0);
      }
    }
#pragma unroll
    for (int g = 0; g < 2; ++g)
      *(half4*)&catl[g][(8 + w) * 256 + l * 16 + q * 4] =
          pk4(acc[g][0], acc[g][1], acc[g][2], acc[g][3]);
  }
  __syncthreads();
  // phase B: h1 tiles 2w, 2w+1 (BN inline; K=32)
#pragma unroll
  for (int i = 0; i < 2; ++i) {
    const int mt = w * 2 + i;
    const v4f bias = *(const v4f*)(bc1 + mt * 16 + q * 4);
    v4f acc[2] = {bias, bias};
#pragma unroll
    for (int kt2 = 0; kt2 < 8; ++kt2) {
      const half8 wp = *(const half8*)(wc1_h + (mt * 16 + l) * 256 + kt2 * 32 + q * 8);
#pragma unroll
      for (int g = 0; g < 2; ++g) {
        const half4 f0 = *(const half4*)&catl[g][(kt2 * 2) * 256 + l * 16 + q * 4];
        const half4 f1 = *(const half4*)&catl[g][(kt2 * 2 + 1) * 256 + l * 16 + q * 4];
        acc[g] = __builtin_amdgcn_mfma_f32_16x16x32_f16(wp, cat8(f0, f1), acc[g], 0, 0, 0);
      }
    }
    const v4f gm = *(const v4f*)(gamma + mt * 16 + q * 4);
    const v4f bt = *(const v4f*)(beta + mt * 16 + q * 4);
    const v4f mn = *(const v4f*)(mean + mt * 16 + q * 4);
    const v4f vr = *(const v4f*)(var + mt * 16 + q * 4);
#pragma unroll
    for (int g = 0; g < 2; ++g) {
      float hh[4];
#pragma unroll
      for (int r = 0; r < 4; ++r) {
        const float a1 = gm[r] * rsqrtf(vr[r] + 1e-5f);
        const float b1 = bt[r] - mn[r] * a1;
        hh[r] = fmaxf(acc[g][r] * a1 + b1, 0.f);
      }
      *(half4*)&exB[g][mt * 256 + l * 16 + q * 4] = pk4(hh[0], hh[1], hh[2], hh[3]);
    }
  }
  __syncthreads();
  {  // phase C: out tile w (K=32)
    const v4f bias = *(const v4f*)(bc2 + w * 16 + q * 4);
    v4f acc[2] = {bias, bias};
#pragma unroll
    for (int kt2 = 0; kt2 < 8; ++kt2) {
      const half8 wp = *(const half8*)(wc2_h + (w * 16 + l) * 256 + kt2 * 32 + q * 8);
#pragma unroll
      for (int g = 0; g < 2; ++g) {
        const half4 f0 = *(const half4*)&exB[g][(kt2 * 2) * 256 + l * 16 + q * 4];
        const half4 f1 = *(const half4*)&exB[g][(kt2 * 2 + 1) * 256 + l * 16 + q * 4];
        acc[g] = __builtin_amdgcn_mfma_f32_16x16x32_f16(wp, cat8(f0, f1), acc[g], 0, 0, 0);
      }
    }
#pragma unroll
    for (int g = 0; g < 2; ++g) {
      const int n = n0 + g * 16 + l;
#pragma unroll
      for (int r = 0; r < 4; ++r)
        out[(size_t)(b * 128 + w * 16 + q * 4 + r) * 2048 + n] =
            acc[g][r] + x1s[g][l * 132 + w * 16 + q * 4 + r];
    }
  }
}

// ---------------------------------------------------------------------------
extern "C" void kernel_launch(void* const* d_in, const int* in_sizes, int n_in,
                              void* d_out, int out_size, void* d_ws,
                              size_t ws_size, hipStream_t stream) {
  const float* x1 = (const float*)d_in[0];
  const float* x2 = (const float*)d_in[1];
  const unsigned char* kv_mask = (const unsigned char*)d_in[2];
  const float* wq = (const float*)d_in[3];
  const float* bq = (const float*)d_in[4];
  const float* wk = (const float*)d_in[5];
  const float* bk = (const float*)d_in[6];
  const float* wv = (const float*)d_in[7];
  const float* bv = (const float*)d_in[8];
  const float* wm = (const float*)d_in[9];
  const float* bm = (const float*)d_in[10];
  const float* wc1 = (const float*)d_in[11];
  const float* bc1 = (const float*)d_in[12];
  const float* bn_gamma = (const float*)d_in[13];
  const float* bn_beta = (const float*)d_in[14];
  const float* bn_mean = (const float*)d_in[15];
  const float* bn_var = (const float*)d_in[16];
  const float* wc2 = (const float*)d_in[17];
  const float* bc2 = (const float*)d_in[18];
  float* out = (float*)d_out;

  // ws: Qpk 2M | Kpk 2M | Vpk 2M | Opk 8M (4 parts) | wts 288K@14M |
  //     lsump 512K@14M+512K | maskf 32K@15M | wqkvh 192K@15M+64K
  char* p = (char*)d_ws;
  _Float16* Qpk = (_Float16*)p;
  _Float16* Kpk = (_Float16*)(p + (size_t)2 * 1024 * 1024);
  _Float16* Vpk = (_Float16*)(p + (size_t)4 * 1024 * 1024);
  _Float16* Opk = (_Float16*)(p + (size_t)6 * 1024 * 1024);
  _Float16* wts = (_Float16*)(p + (size_t)14 * 1024 * 1024);
  float* lsump = (float*)(p + (size_t)14 * 1024 * 1024 + 512 * 1024);
  float* maskf = (float*)(p + (size_t)15 * 1024 * 1024);
  _Float16* wqkvh = (_Float16*)(p + (size_t)15 * 1024 * 1024 + 64 * 1024);

  prep<<<dim3(100), 512, 0, stream>>>(wq, wk, wv, wm, wc1, wc2, kv_mask,
                                      wqkvh, wts, maskf);
  qkv<<<dim3(64, 4), 512, 0, stream>>>(x1, x2, wqkvh, bq, bk, bv, Qpk, Kpk,
                                       Vpk);
  attn<<<dim3(16, 16, 4), 256, 0, stream>>>(Qpk, Kpk, Vpk, maskf, Opk, lsump);
  post<<<dim3(64, 4), 512, 0, stream>>>(x1, Opk, lsump, wts, bm, bc1,
                                        bn_gamma, bn_beta, bn_mean, bn_var,
                                        bc2, out);
}

// Round 8
// 139.137 us; speedup vs baseline: 1.0445x; 1.0445x over previous
//
#include <hip/hip_runtime.h>

// B=4, C=128, H=4, D=32, N=2048.  All-fp16 MFMA pipeline, canonical packed
// fragment format: value block (16ch tile ct, col n, quad q) lives at
// pk[(ct*2048+n)*16 + q*4 + j].
// R9: attn 4-way split + LDS mask bias (161.2).
// R10: 32-col blocks in qkv/post, weight reuse for 2 col groups (143.1).
// R11: prep kernel pre-converts weights to fp16 once (142.5).
// R12: attn denominator on VALU; post kt-paired b128 weight loads (139.5).
// R13 REGRESSED (145.3): K=32 MFMA everywhere saved no matrix cycles
// (MFMA cost is FLOP-proportional on gfx950: 16x16x16 is ~half of
// 16x16x32) while adding cat8 register-assembly VALU + operand pressure.
// R14: exact revert to R12 (best verified).
typedef __attribute__((ext_vector_type(4))) float v4f;
typedef __attribute__((ext_vector_type(8))) _Float16 half8;
typedef __attribute__((ext_vector_type(4))) _Float16 half4;
typedef __attribute__((ext_vector_type(2))) _Float16 half2t;

constexpr float C2 = 0.17677669529663687f * 1.44269504088896341f;  // rsqrt(32)*log2e

__device__ __forceinline__ half4 pk4(float a, float b, float c, float d) {
  half2t lo = __builtin_bit_cast(half2t, __builtin_amdgcn_cvt_pkrtz(a, b));
  half2t hi = __builtin_bit_cast(half2t, __builtin_amdgcn_cvt_pkrtz(c, d));
  return __builtin_shufflevector(lo, hi, 0, 1, 2, 3);
}

// ---------------------------------------------------------------------------
// prep: one-shot weight/mask conversion.  wq|wk|wv -> wqkvh (49152 floats,
// linear).  wm|wc1|wc2 -> wts (147456) with KT-PAIRED layout: within each
// row, dst = (kt>>1)*32 + q4*8 + (kt&1)*4 + j  so a half8 load yields the
// (even,odd) kt fragment pair for one q4.  mask -> maskf (8192).
// grid 100 x 512; one float4 unit per thread (same kt/q4 for all 4 elems).
// ---------------------------------------------------------------------------
__global__ __launch_bounds__(512) void prep(
    const float* __restrict__ wq, const float* __restrict__ wk,
    const float* __restrict__ wv, const float* __restrict__ wm,
    const float* __restrict__ wc1, const float* __restrict__ wc2,
    const unsigned char* __restrict__ mask, _Float16* __restrict__ wqkvh,
    _Float16* __restrict__ wts, float* __restrict__ maskf) {
  const int e = (blockIdx.x * 512 + threadIdx.x) * 4;
  if (e < 49152) {
    const float* src;
    int base;
    if (e < 16384) { src = wq; base = 0; }
    else if (e < 32768) { src = wk; base = 16384; }
    else { src = wv; base = 32768; }
    const float4 t = *(const float4*)(src + (e - base));
    *(half4*)(wqkvh + e) = pk4(t.x, t.y, t.z, t.w);
  } else if (e < 196608) {
    const int e2 = e - 49152;
    const float* src;
    int base, cols;
    if (e2 < 16384) { src = wm; base = 0; cols = 128; }
    else if (e2 < 81920) { src = wc1; base = 16384; cols = 256; }
    else { src = wc2; base = 81920; cols = 256; }
    const int le = e2 - base;
    const int r = le / cols, c = le % cols;
    const int kt = c >> 4, q4 = (c >> 2) & 3;
    const int dst = r * cols + ((kt >> 1) << 5) + (q4 << 3) + ((kt & 1) << 2);
    const float4 t = *(const float4*)(src + le);
    *(half4*)(wts + base + dst) = pk4(t.x, t.y, t.z, t.w);
  } else {
    const int e2 = e - 196608;  // < 8192
    const unsigned mv = *(const unsigned*)(mask + e2);
    float4 o;
    o.x = (mv & 0x000000ffu) ? 0.f : -1.0e6f * C2;
    o.y = (mv & 0x0000ff00u) ? 0.f : -1.0e6f * C2;
    o.z = (mv & 0x00ff0000u) ? 0.f : -1.0e6f * C2;
    o.w = (mv & 0xff000000u) ? 0.f : -1.0e6f * C2;
    *(float4*)(maskf + e2) = o;
  }
}

// ---------------------------------------------------------------------------
// qkv: 32-col blocks, 8 waves; wave w owns 3 of 24 output tiles
// (Q0..7,K8..15,V16..23), each applied to both 16-col groups g=0,1 with ONE
// weight load (fp16, pre-converted).  x1/x2 tiles staged through LDS as fp16
// [g][n][ch] (stride 136).  grid (64,4) x 512.
// ---------------------------------------------------------------------------
__global__ __launch_bounds__(512, 4) void qkv(
    const float* __restrict__ x1, const float* __restrict__ x2,
    const _Float16* __restrict__ wqkvh, const float* __restrict__ bq,
    const float* __restrict__ bk, const float* __restrict__ bv,
    _Float16* __restrict__ Qpk, _Float16* __restrict__ Kpk,
    _Float16* __restrict__ Vpk) {
  const int b = blockIdx.y;
  const int bx = blockIdx.x;  // 32-col group
  const int tid = threadIdx.x, w = tid >> 6, lane = tid & 63;
  const int l = lane & 15, q = lane >> 4;
  const int n0 = bx * 32;
  const _Float16* wqh = wqkvh;
  const _Float16* wkh = wqkvh + 16384;
  const _Float16* wvh = wqkvh + 32768;

  __shared__ _Float16 x1s[2][16 * 136];
  __shared__ _Float16 x2s[2][16 * 136];

  {  // stage x tiles: thread -> (ch, 4 cols) per group, fp32->fp16
    const int ch = tid >> 2, seg = tid & 3;
#pragma unroll
    for (int g = 0; g < 2; ++g) {
      const float4 a =
          *(const float4*)(x1 + (size_t)(b * 128 + ch) * 2048 + n0 + g * 16 + seg * 4);
      const float4 c =
          *(const float4*)(x2 + (size_t)(b * 128 + ch) * 2048 + n0 + g * 16 + seg * 4);
      x1s[g][(seg * 4 + 0) * 136 + ch] = (_Float16)a.x;
      x1s[g][(seg * 4 + 1) * 136 + ch] = (_Float16)a.y;
      x1s[g][(seg * 4 + 2) * 136 + ch] = (_Float16)a.z;
      x1s[g][(seg * 4 + 3) * 136 + ch] = (_Float16)a.w;
      x2s[g][(seg * 4 + 0) * 136 + ch] = (_Float16)c.x;
      x2s[g][(seg * 4 + 1) * 136 + ch] = (_Float16)c.y;
      x2s[g][(seg * 4 + 2) * 136 + ch] = (_Float16)c.z;
      x2s[g][(seg * 4 + 3) * 136 + ch] = (_Float16)c.w;
    }
  }
  __syncthreads();

#pragma unroll
  for (int i = 0; i < 3; ++i) {
    const int t = w * 3 + i;  // wave-uniform
    if (t < 8) {              // Q tile mt=t : out = C2*(wq@x1 + bq)
      const int mt = t;
      half8 wf[4];
#pragma unroll
      for (int kt = 0; kt < 4; ++kt)
        wf[kt] = *(const half8*)(wqh + (mt * 16 + l) * 128 + kt * 32 + q * 8);
      const v4f bias = *(const v4f*)(bq + mt * 16 + q * 4);
#pragma unroll
      for (int g = 0; g < 2; ++g) {
        v4f acc = bias;
#pragma unroll
        for (int kt = 0; kt < 4; ++kt) {
          const half8 xf = *(const half8*)&x1s[g][l * 136 + kt * 32 + q * 8];
          acc = __builtin_amdgcn_mfma_f32_16x16x32_f16(wf[kt], xf, acc, 0, 0, 0);
        }
        *(half4*)(Qpk + ((size_t)(b * 8 + mt) * 2048 + n0 + g * 16 + l) * 16 + q * 4) =
            pk4(acc[0] * C2, acc[1] * C2, acc[2] * C2, acc[3] * C2);
      }
    } else if (t < 16) {  // K tile
      const int mt = t - 8;
      half8 wf[4];
#pragma unroll
      for (int kt = 0; kt < 4; ++kt)
        wf[kt] = *(const half8*)(wkh + (mt * 16 + l) * 128 + kt * 32 + q * 8);
      const v4f bias = *(const v4f*)(bk + mt * 16 + q * 4);
#pragma unroll
      for (int g = 0; g < 2; ++g) {
        v4f acc = bias;
#pragma unroll
        for (int kt = 0; kt < 4; ++kt) {
          const half8 xf = *(const half8*)&x2s[g][l * 136 + kt * 32 + q * 8];
          acc = __builtin_amdgcn_mfma_f32_16x16x32_f16(wf[kt], xf, acc, 0, 0, 0);
        }
        *(half4*)(Kpk + ((size_t)(b * 8 + mt) * 2048 + n0 + g * 16 + l) * 16 + q * 4) =
            pk4(acc[0], acc[1], acc[2], acc[3]);
      }
    } else {  // V^T tile ot (rows = keys of this col-group)
      const int ot = t - 16;
      half8 wf[4];
#pragma unroll
      for (int kt = 0; kt < 4; ++kt)
        wf[kt] = *(const half8*)(wvh + (ot * 16 + l) * 128 + kt * 32 + q * 8);
      const float bvv = bv[ot * 16 + l];
#pragma unroll
      for (int g = 0; g < 2; ++g) {
        v4f acc = {bvv, bvv, bvv, bvv};
#pragma unroll
        for (int kt = 0; kt < 4; ++kt) {
          const half8 xf = *(const half8*)&x2s[g][l * 136 + kt * 32 + q * 8];
          acc = __builtin_amdgcn_mfma_f32_16x16x32_f16(xf, wf[kt], acc, 0, 0, 0);
        }
        const int kx = bx * 2 + g;  // 16-col keytile index
        *(half4*)(Vpk + (((size_t)(b * 4 + (ot >> 1)) * 128 + kx) * 32 +
                         (ot & 1) * 16 + l) * 16 + q * 4) =
            pk4(acc[0], acc[1], acc[2], acc[3]);
      }
    }
  }
}

// ---------------------------------------------------------------------------
// attn: 2 Q-tiles per wave, 4-way key split (512 keys/part, 8 chunks).
// K/V chunks (64 keys) staged in LDS, shared by the block's 4 waves,
// double-buffered with ONE barrier per chunk.  QK 16x16x32 (S^T, mask bias in
// C-init from LDS); exp2 in regs; P regs ARE PV B-frags (16x16x16, V as A).
// Denominator on VALU (24 adds/chunk) + 2-shuffle epilogue — keeps the
// matrix pipe (attn's bottleneck) at its 24-MFMA/chunk minimum.
// s_setprio(1) around MFMA clusters (T5).  grid (16,16,4) x 256.
// ---------------------------------------------------------------------------
__global__ __launch_bounds__(256) void attn(
    const _Float16* __restrict__ Qpk, const _Float16* __restrict__ Kpk,
    const _Float16* __restrict__ Vpk, const float* __restrict__ maskf,
    _Float16* __restrict__ Opk, float* __restrict__ lsump) {
  const int bh = blockIdx.y, b = bh >> 2, h = bh & 3;
  const int part = blockIdx.z;
  const int tid = threadIdx.x, w = tid >> 6, lane = tid & 63;
  const int l = lane & 15, q = lane >> 4;
  const int nb = blockIdx.x * 128 + w * 32;  // wave's 32 queries

  // K: [ct][k][16] rows padded to 24 halfs, ct stride 1544 (bank-skewed).
  // V: [tile][d][16] rows padded to 24 halfs, tile stride 768.
  __shared__ _Float16 ldsK[2][3088];
  __shared__ _Float16 ldsV[2][3072];
  __shared__ __align__(16) float biass[512];  // part's mask bias (2 KB)

  const size_t qrow = (size_t)(b * 8 + h * 2 + (q >> 1)) * 2048;
  const half8 qf0 = *(const half8*)(Qpk + (qrow + nb + l) * 16 + (q & 1) * 8);
  const half8 qf1 = *(const half8*)(Qpk + (qrow + nb + 16 + l) * 16 + (q & 1) * 8);
  const _Float16* __restrict__ Kg = Kpk + (size_t)(b * 8 + h * 2) * 2048 * 16;
  const _Float16* __restrict__ Vg = Vpk + (size_t)((b * 4 + h) * 128) * 512;

  // staging indices (thread-static)
  const int kct = tid >> 7, kk = (tid >> 1) & 63, khf = tid & 1;
  const int vt = tid >> 6, vd = (tid >> 1) & 31;

  v4f oacc[2][2] = {{{0.f, 0.f, 0.f, 0.f}, {0.f, 0.f, 0.f, 0.f}},
                    {{0.f, 0.f, 0.f, 0.f}, {0.f, 0.f, 0.f, 0.f}}};
  float ls0 = 0.f, ls1 = 0.f;
  const int mbeg = part * 512;

  // stage bias (2 KB) + first K/V chunk
  if (tid < 128)
    *(float4*)&biass[tid * 4] = *(const float4*)(maskf + b * 2048 + mbeg + tid * 4);
  half8 kr = *(const half8*)(Kg + ((size_t)kct * 2048 + mbeg + kk) * 16 + khf * 8);
  half8 vr = *(const half8*)(Vg + (size_t)((mbeg >> 4) + vt) * 512 + vd * 16 + khf * 8);
  *(half8*)&ldsK[0][kct * 1544 + kk * 24 + khf * 8] = kr;
  *(half8*)&ldsV[0][vt * 768 + vd * 24 + khf * 8] = vr;
  __syncthreads();

  for (int i = 0; i < 8; ++i) {
    const int m0 = mbeg + i * 64;
    const int cur = i & 1;
    if (i < 7) {  // prefetch next chunk to regs
      kr = *(const half8*)(Kg + ((size_t)kct * 2048 + m0 + 64 + kk) * 16 + khf * 8);
      vr = *(const half8*)(Vg + (size_t)(((m0 + 64) >> 4) + vt) * 512 + vd * 16 + khf * 8);
    }
    half4 pB[2][4];
#pragma unroll
    for (int mt = 0; mt < 4; ++mt) {
      const half8 kf =
          *(const half8*)&ldsK[cur][(q >> 1) * 1544 + (mt * 16 + l) * 24 + (q & 1) * 8];
      const v4f biasv = *(const v4f*)&biass[i * 64 + mt * 16 + q * 4];
      __builtin_amdgcn_s_setprio(1);
      const v4f s0 = __builtin_amdgcn_mfma_f32_16x16x32_f16(kf, qf0, biasv, 0, 0, 0);
      const v4f s1 = __builtin_amdgcn_mfma_f32_16x16x32_f16(kf, qf1, biasv, 0, 0, 0);
      __builtin_amdgcn_s_setprio(0);
      const float a0 = exp2f(s0[0]), a1 = exp2f(s0[1]), a2 = exp2f(s0[2]),
                  a3 = exp2f(s0[3]);
      const float c0 = exp2f(s1[0]), c1 = exp2f(s1[1]), c2 = exp2f(s1[2]),
                  c3 = exp2f(s1[3]);
      ls0 += (a0 + a1) + (a2 + a3);
      ls1 += (c0 + c1) + (c2 + c3);
      pB[0][mt] = pk4(a0, a1, a2, a3);
      pB[1][mt] = pk4(c0, c1, c2, c3);
    }
    __builtin_amdgcn_s_setprio(1);
#pragma unroll
    for (int mt = 0; mt < 4; ++mt) {
      const half4 vf0 = *(const half4*)&ldsV[cur][mt * 768 + l * 24 + q * 4];
      const half4 vf1 = *(const half4*)&ldsV[cur][mt * 768 + (16 + l) * 24 + q * 4];
      oacc[0][0] = __builtin_amdgcn_mfma_f32_16x16x16f16(vf0, pB[0][mt], oacc[0][0], 0, 0, 0);
      oacc[0][1] = __builtin_amdgcn_mfma_f32_16x16x16f16(vf1, pB[0][mt], oacc[0][1], 0, 0, 0);
      oacc[1][0] = __builtin_amdgcn_mfma_f32_16x16x16f16(vf0, pB[1][mt], oacc[1][0], 0, 0, 0);
      oacc[1][1] = __builtin_amdgcn_mfma_f32_16x16x16f16(vf1, pB[1][mt], oacc[1][1], 0, 0, 0);
    }
    __builtin_amdgcn_s_setprio(0);
    if (i < 7) {
      *(half8*)&ldsK[cur ^ 1][kct * 1544 + kk * 24 + khf * 8] = kr;
      *(half8*)&ldsV[cur ^ 1][vt * 768 + vd * 24 + khf * 8] = vr;
      __syncthreads();
    }
  }
  ls0 += __shfl_xor(ls0, 16);
  ls0 += __shfl_xor(ls0, 32);
  ls1 += __shfl_xor(ls1, 16);
  ls1 += __shfl_xor(ls1, 32);
  if (q == 0) {
    lsump[part * 32768 + bh * 2048 + nb + l] = ls0;
    lsump[part * 32768 + bh * 2048 + nb + 16 + l] = ls1;
  }
#pragma unroll
  for (int qt = 0; qt < 2; ++qt)
#pragma unroll
    for (int df = 0; df < 2; ++df)
      *(half4*)(Opk + (size_t)part * 1048576 +
                ((size_t)(b * 8 + h * 2 + df) * 2048 + nb + qt * 16 + l) * 16 +
                q * 4) = pk4(oacc[qt][df][0], oacc[qt][df][1], oacc[qt][df][2],
                             oacc[qt][df][3]);
}

// ---------------------------------------------------------------------------
// post: 32-col blocks, 8 waves; weights loaded as KT-PAIRED half8 (one b128
// load = two kt fragments; layout from prep) and applied to both 16-col
// groups.  O-merge, x1 staged once per block through LDS; cat frags unified
// in catl.  A: wave w -> cat tile 8+w.  B: wave w -> h1 tiles 2w,2w+1 (BN
// inline).  C: wave w -> out tile w.  grid (64,4) x 512.
// ---------------------------------------------------------------------------
__global__ __launch_bounds__(512, 4) void post(
    const float* __restrict__ x1, const _Float16* __restrict__ Opk,
    const float* __restrict__ lsump, const _Float16* __restrict__ wts,
    const float* __restrict__ bm, const float* __restrict__ bc1,
    const float* __restrict__ gamma, const float* __restrict__ beta,
    const float* __restrict__ mean, const float* __restrict__ var,
    const float* __restrict__ bc2, float* __restrict__ out) {
  const int b = blockIdx.y;
  const int n0 = blockIdx.x * 32;
  const int tid = threadIdx.x, w = tid >> 6, lane = tid & 63;
  const int l = lane & 15, q = lane >> 4;
  const _Float16* wm_h = wts;
  const _Float16* wc1_h = wts + 16384;
  const _Float16* wc2_h = wts + 81920;

  __shared__ __align__(16) float x1s[2][16 * 132];     // [g][n][ch] fp32
  __shared__ __align__(16) _Float16 ofs[2][8 * 256];   // merged O
  __shared__ __align__(16) _Float16 catl[2][16 * 256]; // cat frags: x1 | A-out
  __shared__ __align__(16) _Float16 exB[2][16 * 256];  // phase-B outputs

  {  // stage x1 tiles: one float4/thread per group
    const int ch = tid >> 2, seg = tid & 3;
#pragma unroll
    for (int g = 0; g < 2; ++g) {
      const float4 a =
          *(const float4*)(x1 + (size_t)(b * 128 + ch) * 2048 + n0 + g * 16 + seg * 4);
      x1s[g][(seg * 4 + 0) * 132 + ch] = a.x;
      x1s[g][(seg * 4 + 1) * 132 + ch] = a.y;
      x1s[g][(seg * 4 + 2) * 132 + ch] = a.z;
      x1s[g][(seg * 4 + 3) * 132 + ch] = a.w;
    }
  }
  {  // merge O parts once: wave w handles ch-tile kt=w
#pragma unroll
    for (int g = 0; g < 2; ++g) {
      const int n = n0 + g * 16 + l;
      const size_t idx = (size_t)(b * 4 + (w >> 1)) * 2048 + n;
      const float rl = 1.0f / (lsump[idx] + lsump[32768 + idx] +
                               lsump[65536 + idx] + lsump[98304 + idx]);
      const size_t oa = ((size_t)(b * 8 + w) * 2048 + n) * 16 + q * 4;
      const half4 a = *(const half4*)(Opk + oa);
      const half4 c = *(const half4*)(Opk + 1048576 + oa);
      const half4 d = *(const half4*)(Opk + 2097152 + oa);
      const half4 e = *(const half4*)(Opk + 3145728 + oa);
      const _Float16 rh = (_Float16)rl;
      const half4 rl4 = {rh, rh, rh, rh};
      *(half4*)&ofs[g][w * 256 + l * 16 + q * 4] = ((a + c) + (d + e)) * rl4;
    }
  }
  __syncthreads();
  {  // x1 fp16 frags into catl tiles 0..7 (x1s complete after sync)
#pragma unroll
    for (int g = 0; g < 2; ++g) {
      const float4 xv = *(const float4*)&x1s[g][l * 132 + w * 16 + q * 4];
      *(half4*)&catl[g][w * 256 + l * 16 + q * 4] = pk4(xv.x, xv.y, xv.z, xv.w);
    }
  }
  {  // phase A: cat tile 8+w = wm @ O  (kt-paired wm loads)
    const v4f bias = *(const v4f*)(bm + w * 16 + q * 4);
    v4f acc[2] = {bias, bias};
#pragma unroll
    for (int kt2 = 0; kt2 < 4; ++kt2) {
      const half8 wp = *(const half8*)(wm_h + (w * 16 + l) * 128 + kt2 * 32 + q * 8);
      const half4 wlo = __builtin_shufflevector(wp, wp, 0, 1, 2, 3);
      const half4 whi = __builtin_shufflevector(wp, wp, 4, 5, 6, 7);
#pragma unroll
      for (int g = 0; g < 2; ++g) {
        const half4 of0 = *(const half4*)&ofs[g][(kt2 * 2) * 256 + l * 16 + q * 4];
        const half4 of1 = *(const half4*)&ofs[g][(kt2 * 2 + 1) * 256 + l * 16 + q * 4];
        acc[g] = __builtin_amdgcn_mfma_f32_16x16x16f16(wlo, of0, acc[g], 0, 0, 0);
        acc[g] = __builtin_amdgcn_mfma_f32_16x16x16f16(whi, of1, acc[g], 0, 0, 0);
      }
    }
#pragma unroll
    for (int g = 0; g < 2; ++g)
      *(half4*)&catl[g][(8 + w) * 256 + l * 16 + q * 4] =
          pk4(acc[g][0], acc[g][1], acc[g][2], acc[g][3]);
  }
  __syncthreads();
  // phase B: h1 tiles 2w, 2w+1 (BN inline; kt-paired wc1 loads)
#pragma unroll
  for (int i = 0; i < 2; ++i) {
    const int mt = w * 2 + i;
    const v4f bias = *(const v4f*)(bc1 + mt * 16 + q * 4);
    v4f acc[2] = {bias, bias};
#pragma unroll
    for (int kt2 = 0; kt2 < 8; ++kt2) {
      const half8 wp = *(const half8*)(wc1_h + (mt * 16 + l) * 256 + kt2 * 32 + q * 8);
      const half4 wlo = __builtin_shufflevector(wp, wp, 0, 1, 2, 3);
      const half4 whi = __builtin_shufflevector(wp, wp, 4, 5, 6, 7);
#pragma unroll
      for (int g = 0; g < 2; ++g) {
        const half4 f0 = *(const half4*)&catl[g][(kt2 * 2) * 256 + l * 16 + q * 4];
        const half4 f1 = *(const half4*)&catl[g][(kt2 * 2 + 1) * 256 + l * 16 + q * 4];
        acc[g] = __builtin_amdgcn_mfma_f32_16x16x16f16(wlo, f0, acc[g], 0, 0, 0);
        acc[g] = __builtin_amdgcn_mfma_f32_16x16x16f16(whi, f1, acc[g], 0, 0, 0);
      }
    }
    const v4f gm = *(const v4f*)(gamma + mt * 16 + q * 4);
    const v4f bt = *(const v4f*)(beta + mt * 16 + q * 4);
    const v4f mn = *(const v4f*)(mean + mt * 16 + q * 4);
    const v4f vr = *(const v4f*)(var + mt * 16 + q * 4);
#pragma unroll
    for (int g = 0; g < 2; ++g) {
      float hh[4];
#pragma unroll
      for (int r = 0; r < 4; ++r) {
        const float a1 = gm[r] * rsqrtf(vr[r] + 1e-5f);
        const float b1 = bt[r] - mn[r] * a1;
        hh[r] = fmaxf(acc[g][r] * a1 + b1, 0.f);
      }
      *(half4*)&exB[g][mt * 256 + l * 16 + q * 4] = pk4(hh[0], hh[1], hh[2], hh[3]);
    }
  }
  __syncthreads();
  {  // phase C: out tile w (kt-paired wc2 loads)
    const v4f bias = *(const v4f*)(bc2 + w * 16 + q * 4);
    v4f acc[2] = {bias, bias};
#pragma unroll
    for (int kt2 = 0; kt2 < 8; ++kt2) {
      const half8 wp = *(const half8*)(wc2_h + (w * 16 + l) * 256 + kt2 * 32 + q * 8);
      const half4 wlo = __builtin_shufflevector(wp, wp, 0, 1, 2, 3);
      const half4 whi = __builtin_shufflevector(wp, wp, 4, 5, 6, 7);
#pragma unroll
      for (int g = 0; g < 2; ++g) {
        const half4 f0 = *(const half4*)&exB[g][(kt2 * 2) * 256 + l * 16 + q * 4];
        const half4 f1 = *(const half4*)&exB[g][(kt2 * 2 + 1) * 256 + l * 16 + q * 4];
        acc[g] = __builtin_amdgcn_mfma_f32_16x16x16f16(wlo, f0, acc[g], 0, 0, 0);
        acc[g] = __builtin_amdgcn_mfma_f32_16x16x16f16(whi, f1, acc[g], 0, 0, 0);
      }
    }
#pragma unroll
    for (int g = 0; g < 2; ++g) {
      const int n = n0 + g * 16 + l;
#pragma unroll
      for (int r = 0; r < 4; ++r)
        out[(size_t)(b * 128 + w * 16 + q * 4 + r) * 2048 + n] =
            acc[g][r] + x1s[g][l * 132 + w * 16 + q * 4 + r];
    }
  }
}

// ---------------------------------------------------------------------------
extern "C" void kernel_launch(void* const* d_in, const int* in_sizes, int n_in,
                              void* d_out, int out_size, void* d_ws,
                              size_t ws_size, hipStream_t stream) {
  const float* x1 = (const float*)d_in[0];
  const float* x2 = (const float*)d_in[1];
  const unsigned char* kv_mask = (const unsigned char*)d_in[2];
  const float* wq = (const float*)d_in[3];
  const float* bq = (const float*)d_in[4];
  const float* wk = (const float*)d_in[5];
  const float* bk = (const float*)d_in[6];
  const float* wv = (const float*)d_in[7];
  const float* bv = (const float*)d_in[8];
  const float* wm = (const float*)d_in[9];
  const float* bm = (const float*)d_in[10];
  const float* wc1 = (const float*)d_in[11];
  const float* bc1 = (const float*)d_in[12];
  const float* bn_gamma = (const float*)d_in[13];
  const float* bn_beta = (const float*)d_in[14];
  const float* bn_mean = (const float*)d_in[15];
  const float* bn_var = (const float*)d_in[16];
  const float* wc2 = (const float*)d_in[17];
  const float* bc2 = (const float*)d_in[18];
  float* out = (float*)d_out;

  // ws: Qpk 2M | Kpk 2M | Vpk 2M | Opk 8M (4 parts) | wts 288K@14M |
  //     lsump 512K@14M+512K | maskf 32K@15M | wqkvh 192K@15M+64K
  char* p = (char*)d_ws;
  _Float16* Qpk = (_Float16*)p;
  _Float16* Kpk = (_Float16*)(p + (size_t)2 * 1024 * 1024);
  _Float16* Vpk = (_Float16*)(p + (size_t)4 * 1024 * 1024);
  _Float16* Opk = (_Float16*)(p + (size_t)6 * 1024 * 1024);
  _Float16* wts = (_Float16*)(p + (size_t)14 * 1024 * 1024);
  float* lsump = (float*)(p + (size_t)14 * 1024 * 1024 + 512 * 1024);
  float* maskf = (float*)(p + (size_t)15 * 1024 * 1024);
  _Float16* wqkvh = (_Float16*)(p + (size_t)15 * 1024 * 1024 + 64 * 1024);

  prep<<<dim3(100), 512, 0, stream>>>(wq, wk, wv, wm, wc1, wc2, kv_mask,
                                      wqkvh, wts, maskf);
  qkv<<<dim3(64, 4), 512, 0, stream>>>(x1, x2, wqkvh, bq, bk, bv, Qpk, Kpk,
                                       Vpk);
  attn<<<dim3(16, 16, 4), 256, 0, stream>>>(Qpk, Kpk, Vpk, maskf, Opk, lsump);
  post<<<dim3(64, 4), 512, 0, stream>>>(x1, Opk, lsump, wts, bm, bc1,
                                        bn_gamma, bn_beta, bn_mean, bn_var,
                                        bc2, out);
}